// Round 1
// 1502.517 us; speedup vs baseline: 1.0291x; 1.0291x over previous
//
#include <hip/hip_runtime.h>
#include <stdint.h>

// Problem constants (dense MoE: router_indices UNUSED by the reference)
#define NE 32
#define ND 2048
#define NF 768
#define NF2 1536        // 2F
#define NT 2048
#define NEF (NE * NF)   // 24576
#define KH 12288        // W2 K-half (slab path)

// Tile config
#define BM 128
#define BN 64
#define BK 32
#define BSTR 40     // legacy-path LDS B stride

typedef __attribute__((ext_vector_type(8))) short short8;
typedef __attribute__((ext_vector_type(4))) float floatx4;

__device__ __forceinline__ unsigned pk_bf16(float a, float b) {
  union { float f; unsigned u; } ua, ub;
  ua.f = a; ub.f = b;
  unsigned ra = (ua.u + 0x7fffu + ((ua.u >> 16) & 1u)) >> 16;
  unsigned rb = (ub.u + 0x7fffu + ((ub.u >> 16) & 1u)) & 0xffff0000u;
  return ra | rb;
}
__device__ __forceinline__ unsigned short bf16_1(float a) {
  union { float f; unsigned u; } ua; ua.f = a;
  return (unsigned short)((ua.u + 0x7fffu + ((ua.u >> 16) & 1u)) >> 16);
}

#define GLOAD_LDS16(g, l)                                                     \
  __builtin_amdgcn_global_load_lds(                                           \
      (const __attribute__((address_space(1))) void*)(g),                     \
      (__attribute__((address_space(3))) void*)(l), 16, 0, 0)

// ---------------------------------------------------------------- X -> bf16
__global__ void k_cvt_x(const float* __restrict__ x, unsigned short* __restrict__ xb, int n4) {
  int i = blockIdx.x * blockDim.x + threadIdx.x;
  if (i < n4) {
    float4 v = ((const float4*)x)[i];
    uint2 o;
    o.x = pk_bf16(v.x, v.y);
    o.y = pk_bf16(v.z, v.w);
    ((uint2*)xb)[i] = o;
  }
}

// ------------------------------------ fp32 [R][C] -> bf16 [C][R] transpose
// 64x64 tile, 256 threads. blockIdx.z selects sub-matrix (stride zstride elems
// on both sides -- in/out have equal element counts). Out row stride == R.
__global__ void k_trans(const float* __restrict__ in, unsigned short* __restrict__ out,
                        int R, int C, size_t zstride) {
  __shared__ float sT[64][65];
  in  += (size_t)blockIdx.z * zstride;
  out += (size_t)blockIdx.z * zstride;
  const int r0 = blockIdx.y * 64, c0 = blockIdx.x * 64;
  const int t = threadIdx.x;
  const int lrow = t >> 4, lc4 = (t & 15) * 4;
#pragma unroll
  for (int i = 0; i < 4; i++) {
    float4 v = *(const float4*)&in[(size_t)(r0 + lrow + i * 16) * C + c0 + lc4];
    sT[lrow + i * 16][lc4 + 0] = v.x;
    sT[lrow + i * 16][lc4 + 1] = v.y;
    sT[lrow + i * 16][lc4 + 2] = v.z;
    sT[lrow + i * 16][lc4 + 3] = v.w;
  }
  __syncthreads();
  const int c = t >> 2, rg = (t & 3) * 16;
  uint4 o0, o1;
  o0.x = pk_bf16(sT[rg + 0][c],  sT[rg + 1][c]);
  o0.y = pk_bf16(sT[rg + 2][c],  sT[rg + 3][c]);
  o0.z = pk_bf16(sT[rg + 4][c],  sT[rg + 5][c]);
  o0.w = pk_bf16(sT[rg + 6][c],  sT[rg + 7][c]);
  o1.x = pk_bf16(sT[rg + 8][c],  sT[rg + 9][c]);
  o1.y = pk_bf16(sT[rg + 10][c], sT[rg + 11][c]);
  o1.z = pk_bf16(sT[rg + 12][c], sT[rg + 13][c]);
  o1.w = pk_bf16(sT[rg + 14][c], sT[rg + 15][c]);
  unsigned short* op = &out[(size_t)(c0 + c) * R + r0 + rg];
  ((uint4*)op)[0] = o0;
  ((uint4*)op)[1] = o1;
}

// ---------------------- Phase A (bf16 path): X @ W1t + silu-gate -> gated'
// w1t: experts, each [NF2][ND] bf16 (gate rows 0..NF-1, up rows NF..NF2-1)
// grid: (16 mtiles * 12 ntiles, n_experts), 256 threads
__global__ __launch_bounds__(256, 3) void k_gemm1b(
    const unsigned short* __restrict__ xb,   // NT x ND bf16
    const unsigned short* __restrict__ w1t,  // nE x NF2 x ND bf16
    const float* __restrict__ rw,            // NT x NE fp32
    unsigned short* __restrict__ gws,        // NT x NEF bf16
    int e0)
{
  __shared__ unsigned short sA[BM * BK];   // [m][k], 64B rows
  __shared__ unsigned short sG[BN * BK];   // [n][k]
  __shared__ unsigned short sU[BN * BK];
  __shared__ float srw[BM];

  const int el  = blockIdx.y;             // local expert
  const int e   = e0 + el;
  const int mt  = blockIdx.x & 15;        // mtile fastest -> W1-tile sharers adjacent
  const int nt  = blockIdx.x >> 4;        // 0..11
  const int m0  = mt * BM, n0 = nt * BN;
  const int tid = threadIdx.x;
  const int wid = tid >> 6, lane = tid & 63;
  const int wm = wid >> 1, wn = wid & 1;
  const int l15 = lane & 15, q = lane >> 4;

  if (tid < BM) srw[tid] = rw[(size_t)(m0 + tid) * NE + e];

  floatx4 accG[4][2], accU[4][2];
#pragma unroll
  for (int i = 0; i < 4; i++)
#pragma unroll
    for (int j = 0; j < 2; j++) {
      accG[i][j] = (floatx4){0.f, 0.f, 0.f, 0.f};
      accU[i][j] = (floatx4){0.f, 0.f, 0.f, 0.f};
    }

  const unsigned short* w1e = w1t + (size_t)el * NF2 * ND;

  // A staging: wave stages rows [wid*32, wid*32+32), 2 x glds16
  const int koff = (lane & 3) * 8;
  const unsigned short* aptr = xb + (size_t)(m0 + wid * 32 + (lane >> 2)) * ND + koff;
  unsigned short* aLds = &sA[wid * 32 * BK];
  // G/U staging: wave stages rows [wid*16, wid*16+16), 1 x glds16 each
  const unsigned short* gptr = w1e + (size_t)(n0 + wid * 16 + (lane >> 2)) * ND + koff;
  const unsigned short* uptr = gptr + (size_t)NF * ND;
  unsigned short* gLds = &sG[wid * 16 * BK];
  unsigned short* uLds = &sU[wid * 16 * BK];

  for (int kb = 0; kb < ND / BK; ++kb) {
    __syncthreads();  // prior iteration's LDS reads done
    GLOAD_LDS16(aptr + kb * BK, aLds);
    GLOAD_LDS16(aptr + kb * BK + 16 * ND, aLds + 16 * BK);
    GLOAD_LDS16(gptr + kb * BK, gLds);
    GLOAD_LDS16(uptr + kb * BK, uLds);
    __syncthreads();  // staging visible (barrier drains vmcnt)

    short8 bg0 = *(const short8*)&sG[(wn * 32 + 0  + l15) * BK + q * 8];
    short8 bg1 = *(const short8*)&sG[(wn * 32 + 16 + l15) * BK + q * 8];
    short8 bu0 = *(const short8*)&sU[(wn * 32 + 0  + l15) * BK + q * 8];
    short8 bu1 = *(const short8*)&sU[(wn * 32 + 16 + l15) * BK + q * 8];
#pragma unroll
    for (int i = 0; i < 4; i++) {
      short8 af = *(const short8*)&sA[(wm * 64 + i * 16 + l15) * BK + q * 8];
      accG[i][0] = __builtin_amdgcn_mfma_f32_16x16x32_bf16(af, bg0, accG[i][0], 0, 0, 0);
      accG[i][1] = __builtin_amdgcn_mfma_f32_16x16x32_bf16(af, bg1, accG[i][1], 0, 0, 0);
      accU[i][0] = __builtin_amdgcn_mfma_f32_16x16x32_bf16(af, bu0, accU[i][0], 0, 0, 0);
      accU[i][1] = __builtin_amdgcn_mfma_f32_16x16x32_bf16(af, bu1, accU[i][1], 0, 0, 0);
    }
  }

  // Epilogue: gated' = up * silu(gate) * rw, store bf16
  const size_t obase = (size_t)m0 * NEF + (size_t)e * NF + n0 + wn * 32;
#pragma unroll
  for (int i = 0; i < 4; i++)
#pragma unroll
    for (int j = 0; j < 2; j++)
#pragma unroll
      for (int r = 0; r < 4; r++) {
        int row = wm * 64 + i * 16 + q * 4 + r;
        float g = accG[i][j][r];
        float u = accU[i][j][r];
        float sig = __builtin_amdgcn_rcpf(1.f + __expf(-g));
        float val = u * g * sig * srw[row];
        gws[obase + (size_t)row * NEF + j * 16 + l15] = bf16_1(val);
      }
}

// ---------------------- Phase B (bf16 path): gated' @ W2t -> out (atomic)
// w2t: [ND][KSTRIDE] bf16 slab (transposed W2, row stride KSTRIDE)
// grid: (16 mtiles * 32 ntiles, ksplits), 256 threads
template<int KSTRIDE, int HITERS>
__global__ __launch_bounds__(256, 3) void k_gemm2b(
    const unsigned short* __restrict__ gb,   // NT x NEF bf16
    const unsigned short* __restrict__ w2t,  // ND x KSTRIDE bf16
    float* __restrict__ out,                 // NT x ND fp32 (pre-zeroed)
    int kbase)                               // global gb-k offset of this slab
{
  __shared__ unsigned short sA[BM * BK];
  __shared__ unsigned short sB[BN * BK];

  const int mt = blockIdx.x & 15;
  const int nt = blockIdx.x >> 4;   // 0..31
  const int m0 = mt * BM, n0 = nt * BN;
  const int tid = threadIdx.x;
  const int wid = tid >> 6, lane = tid & 63;
  const int wm = wid >> 1, wn = wid & 1;
  const int l15 = lane & 15, q = lane >> 4;

  const int kb0 = blockIdx.y * HITERS;
  const int kb1 = kb0 + HITERS;

  floatx4 acc[4][2];
#pragma unroll
  for (int i = 0; i < 4; i++)
#pragma unroll
    for (int j = 0; j < 2; j++) acc[i][j] = (floatx4){0.f, 0.f, 0.f, 0.f};

  const int koff = (lane & 3) * 8;
  const unsigned short* aptr = gb + (size_t)(m0 + wid * 32 + (lane >> 2)) * NEF + kbase + koff;
  unsigned short* aLds = &sA[wid * 32 * BK];
  const unsigned short* bptr = w2t + (size_t)(n0 + wid * 16 + (lane >> 2)) * KSTRIDE + koff;
  unsigned short* bLds = &sB[wid * 16 * BK];

  for (int kb = kb0; kb < kb1; ++kb) {
    __syncthreads();
    GLOAD_LDS16(aptr + kb * BK, aLds);
    GLOAD_LDS16(aptr + kb * BK + 16 * NEF, aLds + 16 * BK);
    GLOAD_LDS16(bptr + kb * BK, bLds);
    __syncthreads();

    short8 b0 = *(const short8*)&sB[(wn * 32 + 0  + l15) * BK + q * 8];
    short8 b1 = *(const short8*)&sB[(wn * 32 + 16 + l15) * BK + q * 8];
#pragma unroll
    for (int i = 0; i < 4; i++) {
      short8 af = *(const short8*)&sA[(wm * 64 + i * 16 + l15) * BK + q * 8];
      acc[i][0] = __builtin_amdgcn_mfma_f32_16x16x32_bf16(af, b0, acc[i][0], 0, 0, 0);
      acc[i][1] = __builtin_amdgcn_mfma_f32_16x16x32_bf16(af, b1, acc[i][1], 0, 0, 0);
    }
  }

#pragma unroll
  for (int i = 0; i < 4; i++)
#pragma unroll
    for (int j = 0; j < 2; j++)
#pragma unroll
      for (int r = 0; r < 4; r++) {
        int row = wm * 64 + i * 16 + q * 4 + r;
        unsafeAtomicAdd(&out[(size_t)(m0 + row) * ND + n0 + wn * 32 + j * 16 + l15],
                        acc[i][j][r]);
      }
}

// ======================= legacy fp32-weight path (ws fallback) =============
__global__ __launch_bounds__(256, 2) void k_gemm1_legacy(
    const unsigned short* __restrict__ xb, const float* __restrict__ w1,
    const float* __restrict__ rw, unsigned short* __restrict__ gws)
{
  __shared__ unsigned short sA[BM * BK];
  __shared__ unsigned short sG[BN * BSTR];
  __shared__ unsigned short sU[BN * BSTR];
  __shared__ float srw[BM];
  const int e = blockIdx.y, mt = blockIdx.x & 15, nt = blockIdx.x >> 4;
  const int m0 = mt * BM, n0 = nt * BN;
  const int tid = threadIdx.x, wid = tid >> 6, lane = tid & 63;
  const int wm = wid >> 1, wn = wid & 1, l15 = lane & 15, q = lane >> 4;
  if (tid < BM) srw[tid] = rw[(size_t)(m0 + tid) * NE + e];
  const float* w1e = w1 + (size_t)e * ND * (2 * NF);
  floatx4 accG[4][2], accU[4][2];
#pragma unroll
  for (int i = 0; i < 4; i++)
#pragma unroll
    for (int j = 0; j < 2; j++) {
      accG[i][j] = (floatx4){0.f, 0.f, 0.f, 0.f};
      accU[i][j] = (floatx4){0.f, 0.f, 0.f, 0.f};
    }
  const int arow = wid * 32 + (lane >> 2), akoff = (lane & 3) * 8;
  const unsigned short* aptr = xb + (size_t)(m0 + arow) * ND + akoff;
  unsigned short* aLds = &sA[wid * 32 * BK];
  const float* gptr0 = w1e + (size_t)(wid * 8) * (2 * NF) + n0 + lane;
  for (int kb = 0; kb < ND / BK; ++kb) {
    const float* gp = gptr0 + (size_t)kb * BK * (2 * NF);
    float gv[8], uv[8];
#pragma unroll
    for (int r = 0; r < 8; r++) {
      gv[r] = gp[(size_t)r * (2 * NF)];
      uv[r] = gp[(size_t)r * (2 * NF) + NF];
    }
    __syncthreads();
    GLOAD_LDS16(aptr + kb * BK, aLds);
    GLOAD_LDS16(aptr + kb * BK + 16 * ND, aLds + 16 * BK);
    uint4 wg, wu;
    wg.x = pk_bf16(gv[0], gv[1]); wg.y = pk_bf16(gv[2], gv[3]);
    wg.z = pk_bf16(gv[4], gv[5]); wg.w = pk_bf16(gv[6], gv[7]);
    wu.x = pk_bf16(uv[0], uv[1]); wu.y = pk_bf16(uv[2], uv[3]);
    wu.z = pk_bf16(uv[4], uv[5]); wu.w = pk_bf16(uv[6], uv[7]);
    *((uint4*)&sG[lane * BSTR + wid * 8]) = wg;
    *((uint4*)&sU[lane * BSTR + wid * 8]) = wu;
    __syncthreads();
    short8 bg0 = *(const short8*)&sG[(wn * 32 + 0  + l15) * BSTR + q * 8];
    short8 bg1 = *(const short8*)&sG[(wn * 32 + 16 + l15) * BSTR + q * 8];
    short8 bu0 = *(const short8*)&sU[(wn * 32 + 0  + l15) * BSTR + q * 8];
    short8 bu1 = *(const short8*)&sU[(wn * 32 + 16 + l15) * BSTR + q * 8];
#pragma unroll
    for (int i = 0; i < 4; i++) {
      short8 af = *(const short8*)&sA[(wm * 64 + i * 16 + l15) * BK + q * 8];
      accG[i][0] = __builtin_amdgcn_mfma_f32_16x16x32_bf16(af, bg0, accG[i][0], 0, 0, 0);
      accG[i][1] = __builtin_amdgcn_mfma_f32_16x16x32_bf16(af, bg1, accG[i][1], 0, 0, 0);
      accU[i][0] = __builtin_amdgcn_mfma_f32_16x16x32_bf16(af, bu0, accU[i][0], 0, 0, 0);
      accU[i][1] = __builtin_amdgcn_mfma_f32_16x16x32_bf16(af, bu1, accU[i][1], 0, 0, 0);
    }
  }
  const size_t obase = (size_t)m0 * NEF + (size_t)e * NF + n0 + wn * 32;
#pragma unroll
  for (int i = 0; i < 4; i++)
#pragma unroll
    for (int j = 0; j < 2; j++)
#pragma unroll
      for (int r = 0; r < 4; r++) {
        int row = wm * 64 + i * 16 + q * 4 + r;
        float g = accG[i][j][r], u = accU[i][j][r];
        float sig = __builtin_amdgcn_rcpf(1.f + __expf(-g));
        gws[obase + (size_t)row * NEF + j * 16 + l15] = bf16_1(u * g * sig * srw[row]);
      }
}

__global__ __launch_bounds__(256, 2) void k_gemm2_legacy(
    const unsigned short* __restrict__ gb, const float* __restrict__ w2,
    float* __restrict__ out)
{
  __shared__ unsigned short sA[BM * BK];
  __shared__ unsigned short sB[BN * BSTR];
  const int mt = blockIdx.x & 15, nt = blockIdx.x >> 4;
  const int m0 = mt * BM, n0 = nt * BN;
  const int tid = threadIdx.x, wid = tid >> 6, lane = tid & 63;
  const int wm = wid >> 1, wn = wid & 1, l15 = lane & 15, q = lane >> 4;
  const int kb0 = blockIdx.y * (NEF / BK / 4), kb1 = kb0 + (NEF / BK / 4);
  floatx4 acc[4][2];
#pragma unroll
  for (int i = 0; i < 4; i++)
#pragma unroll
    for (int j = 0; j < 2; j++) acc[i][j] = (floatx4){0.f, 0.f, 0.f, 0.f};
  const int arow = wid * 32 + (lane >> 2), akoff = (lane & 3) * 8;
  const unsigned short* aptr = gb + (size_t)(m0 + arow) * NEF + akoff;
  unsigned short* aLds = &sA[wid * 32 * BK];
  const float* bptr0 = w2 + (size_t)(wid * 8) * ND + n0 + lane;
  for (int kb = kb0; kb < kb1; ++kb) {
    const float* bp = bptr0 + (size_t)kb * BK * ND;
    float bv[8];
#pragma unroll
    for (int r = 0; r < 8; r++) bv[r] = bp[(size_t)r * ND];
    __syncthreads();
    GLOAD_LDS16(aptr + kb * BK, aLds);
    GLOAD_LDS16(aptr + kb * BK + 16 * NEF, aLds + 16 * BK);
    uint4 wb;
    wb.x = pk_bf16(bv[0], bv[1]); wb.y = pk_bf16(bv[2], bv[3]);
    wb.z = pk_bf16(bv[4], bv[5]); wb.w = pk_bf16(bv[6], bv[7]);
    *((uint4*)&sB[lane * BSTR + wid * 8]) = wb;
    __syncthreads();
    short8 b0 = *(const short8*)&sB[(wn * 32 + 0  + l15) * BSTR + q * 8];
    short8 b1 = *(const short8*)&sB[(wn * 32 + 16 + l15) * BSTR + q * 8];
#pragma unroll
    for (int i = 0; i < 4; i++) {
      short8 af = *(const short8*)&sA[(wm * 64 + i * 16 + l15) * BK + q * 8];
      acc[i][0] = __builtin_amdgcn_mfma_f32_16x16x32_bf16(af, b0, acc[i][0], 0, 0, 0);
      acc[i][1] = __builtin_amdgcn_mfma_f32_16x16x32_bf16(af, b1, acc[i][1], 0, 0, 0);
    }
  }
#pragma unroll
  for (int i = 0; i < 4; i++)
#pragma unroll
    for (int j = 0; j < 2; j++)
#pragma unroll
      for (int r = 0; r < 4; r++) {
        int row = wm * 64 + i * 16 + q * 4 + r;
        unsafeAtomicAdd(&out[(size_t)(m0 + row) * ND + n0 + wn * 32 + j * 16 + l15],
                        acc[i][j][r]);
      }
}

// ---------------------------------------------------------------------------
extern "C" void kernel_launch(void* const* d_in, const int* in_sizes, int n_in,
                              void* d_out, int out_size, void* d_ws, size_t ws_size,
                              hipStream_t stream) {
  const float* x  = (const float*)d_in[0];   // hidden_states (T,D)
  const float* rw = (const float*)d_in[1];   // routing_weights (T,E)
  // d_in[2] router_indices: unused by reference
  const float* w1 = (const float*)d_in[3];   // gate_up_proj (E,D,2F)
  const float* w2 = (const float*)d_in[4];   // down_proj (E,F,D)
  float* out = (float*)d_out;

  // ws layouts:
  //  full: [xb 8MB][gb 100.7MB][w1t 201.3MB][w2t 100.7MB] = 411 MB
  //  slab: [xb 8MB][gb 100.7MB][wtb 50.3MB]               = 159.4 MB
  unsigned short* xb  = (unsigned short*)d_ws;
  unsigned short* gb  = xb + (size_t)NT * ND;
  unsigned short* wtb = gb + (size_t)NT * NEF;              // slab scratch / w1t base
  unsigned short* w1t = wtb;
  unsigned short* w2t = w1t + (size_t)NE * NF2 * ND;
  const size_t WS_FULL = ((size_t)NT * ND + (size_t)NT * NEF +
                          (size_t)NE * NF2 * ND + (size_t)ND * NEF) * 2;  // 411 MB
  const size_t WS_NEED = ((size_t)NT * ND + (size_t)NT * NEF +
                          (size_t)8 * NF2 * ND) * 2;  // 159.4 MB

  hipMemsetAsync(out, 0, (size_t)out_size * sizeof(float), stream);
  k_cvt_x<<<(NT * ND / 4 + 255) / 256, 256, 0, stream>>>(x, xb, NT * ND / 4);

  if (ws_size >= WS_FULL) {
    // -------- full path: all weights transposed up front, 1 dispatch/GEMM
    {
      dim3 gt(NF2 / 64, ND / 64, NE);   // 24 x 32 x 32 -- all of W1
      k_trans<<<gt, 256, 0, stream>>>(w1, w1t, ND, NF2, (size_t)ND * NF2);
    }
    {
      dim3 gt(ND / 64, NEF / 64, 1);    // 32 x 384 -- all of W2 ([NEF][ND] -> [ND][NEF])
      k_trans<<<gt, 256, 0, stream>>>(w2, w2t, NEF, ND, 0);
    }
    {
      dim3 g1(16 * (NF / BN), NE);      // 192 x 32 = 6144 blocks
      k_gemm1b<<<g1, 256, 0, stream>>>(xb, w1t, rw, gb, 0);
    }
    {
      dim3 g2(16 * (ND / BN), 2);       // 512 x 2, k-split over full NEF
      k_gemm2b<NEF, NEF / BK / 2><<<g2, 256, 0, stream>>>(gb, w2t, out, 0);
    }
  } else if (ws_size >= WS_NEED) {
    // -------- slab path (previous structure)
    for (int qc = 0; qc < 4; ++qc) {
      dim3 gt(NF2 / 64, ND / 64, 8);  // 24 x 32 x 8
      k_trans<<<gt, 256, 0, stream>>>(w1 + (size_t)qc * 8 * ND * NF2, wtb,
                                      ND, NF2, (size_t)ND * NF2);
      dim3 g1(16 * (NF / BN), 8);     // 192 x 8
      k_gemm1b<<<g1, 256, 0, stream>>>(xb, wtb, rw, gb, qc * 8);
    }
    for (int h = 0; h < 2; ++h) {
      dim3 gt(ND / 64, KH / 64, 1);   // 32 x 192
      k_trans<<<gt, 256, 0, stream>>>(w2 + (size_t)h * KH * ND, wtb, KH, ND, 0);
      dim3 g2(16 * (ND / BN), 2);     // 512 x 2
      k_gemm2b<KH, KH / BK / 2><<<g2, 256, 0, stream>>>(gb, wtb, out, h * KH);
    }
  } else {
    // legacy fp32-weight path (R2 structure)
    dim3 gA(16 * (NF / BN), NE);
    k_gemm1_legacy<<<gA, 256, 0, stream>>>(xb, w1, rw, gb);
    dim3 gB(16 * (ND / BN), 4);
    k_gemm2_legacy<<<gB, 256, 0, stream>>>(gb, w2, out);
  }
}

// Round 2
// 1425.643 us; speedup vs baseline: 1.0845x; 1.0539x over previous
//
#include <hip/hip_runtime.h>
#include <stdint.h>

// Problem constants (dense MoE: router_indices UNUSED by the reference)
#define NE 32
#define ND 2048
#define NF 768
#define NF2 1536        // 2F
#define NT 2048
#define NEF (NE * NF)   // 24576
#define KH 12288        // W2 K-half (slab path)

// Tile config (2-phase kernels)
#define BM 128
#define BN 64
#define BK 32
#define BSTR 40     // legacy-path LDS B stride

typedef __attribute__((ext_vector_type(8))) short short8;
typedef __attribute__((ext_vector_type(4))) float floatx4;

__device__ __forceinline__ unsigned pk_bf16(float a, float b) {
  union { float f; unsigned u; } ua, ub;
  ua.f = a; ub.f = b;
  unsigned ra = (ua.u + 0x7fffu + ((ua.u >> 16) & 1u)) >> 16;
  unsigned rb = (ub.u + 0x7fffu + ((ub.u >> 16) & 1u)) & 0xffff0000u;
  return ra | rb;
}
__device__ __forceinline__ unsigned short bf16_1(float a) {
  union { float f; unsigned u; } ua; ua.f = a;
  return (unsigned short)((ua.u + 0x7fffu + ((ua.u >> 16) & 1u)) >> 16);
}

#define GLOAD_LDS16(g, l)                                                     \
  __builtin_amdgcn_global_load_lds(                                           \
      (const __attribute__((address_space(1))) void*)(g),                     \
      (__attribute__((address_space(3))) void*)(l), 16, 0, 0)

#define MF(a, b, c) __builtin_amdgcn_mfma_f32_16x16x32_bf16(a, b, c, 0, 0, 0)

// ---------------------------------------------------------------- X -> bf16
__global__ void k_cvt_x(const float* __restrict__ x, unsigned short* __restrict__ xb, int n4) {
  int i = blockIdx.x * blockDim.x + threadIdx.x;
  if (i < n4) {
    float4 v = ((const float4*)x)[i];
    uint2 o;
    o.x = pk_bf16(v.x, v.y);
    o.y = pk_bf16(v.z, v.w);
    ((uint2*)xb)[i] = o;
  }
}

// ------------------------------------ fp32 [R][C] -> bf16 [C][R] transpose
// 64x64 tile, 256 threads. blockIdx.z selects sub-matrix (stride zstride elems
// on both sides). Out row stride == R.
// PAIR=1: permute output rows so each 64-row group = 32 gate rows + the 32
// matching up rows (gate col c -> row (c/32)*64 + c%32; up col c ->
// (c/32)*64 + 32 + c%32). Used for W1 so the gemm1 epilogue pairs gate/up
// in-register.
template <int PAIR>
__global__ void k_trans(const float* __restrict__ in, unsigned short* __restrict__ out,
                        int R, int C, size_t zstride) {
  __shared__ float sT[64][65];
  in  += (size_t)blockIdx.z * zstride;
  out += (size_t)blockIdx.z * zstride;
  const int r0 = blockIdx.y * 64, c0 = blockIdx.x * 64;
  const int t = threadIdx.x;
  const int lrow = t >> 4, lc4 = (t & 15) * 4;
#pragma unroll
  for (int i = 0; i < 4; i++) {
    float4 v = *(const float4*)&in[(size_t)(r0 + lrow + i * 16) * C + c0 + lc4];
    sT[lrow + i * 16][lc4 + 0] = v.x;
    sT[lrow + i * 16][lc4 + 1] = v.y;
    sT[lrow + i * 16][lc4 + 2] = v.z;
    sT[lrow + i * 16][lc4 + 3] = v.w;
  }
  __syncthreads();
  const int c = t >> 2, rg = (t & 3) * 16;
  uint4 o0, o1;
  o0.x = pk_bf16(sT[rg + 0][c],  sT[rg + 1][c]);
  o0.y = pk_bf16(sT[rg + 2][c],  sT[rg + 3][c]);
  o0.z = pk_bf16(sT[rg + 4][c],  sT[rg + 5][c]);
  o0.w = pk_bf16(sT[rg + 6][c],  sT[rg + 7][c]);
  o1.x = pk_bf16(sT[rg + 8][c],  sT[rg + 9][c]);
  o1.y = pk_bf16(sT[rg + 10][c], sT[rg + 11][c]);
  o1.z = pk_bf16(sT[rg + 12][c], sT[rg + 13][c]);
  o1.w = pk_bf16(sT[rg + 14][c], sT[rg + 15][c]);
  int oc = c0 + c;
  if (PAIR) {
    oc = (oc < NF) ? (((oc >> 5) << 6) + (oc & 31))
                   : ((((oc - NF) >> 5) << 6) + 32 + ((oc - NF) & 31));
  }
  unsigned short* op = &out[(size_t)oc * R + r0 + rg];
  ((uint4*)op)[0] = o0;
  ((uint4*)op)[1] = o1;
}

// ===================== Phase A: 8-phase 256x256xBK64 pipelined GEMM ========
// X @ W1t^T + silu-gate -> gated' (bf16). w1t rows pair-permuted (see k_trans).
// 512 threads = 8 waves (2M x 4N); per-wave C = 128x64; 16 MFMA/phase;
// counted vmcnt(4) at phases 4/8 only; LDS XOR-swizzle (both-sides, rule #21).
__global__ __launch_bounds__(512, 2) void k_gemm1p(
    const unsigned short* __restrict__ xb,   // NT x ND bf16
    const unsigned short* __restrict__ w1t,  // NE x NF2 x ND bf16 (pair-permuted rows)
    const float* __restrict__ rw,            // NT x NE fp32
    unsigned short* __restrict__ gws)        // NT x NEF bf16
{
  __shared__ unsigned short sA[2][2][8192];  // [buf][half][128*64]
  __shared__ unsigned short sB[2][2][8192];
  __shared__ float srw[256];

  // XCD-aware bijective swizzle (nwg = 1536, %8 == 0)
  const int bx = blockIdx.x;
  const int L  = (bx & 7) * 192 + (bx >> 3);
  const int e  = L / 48;
  const int rem = L - e * 48;
  const int mt = rem & 7, nt = rem >> 3;     // 8 mtiles x 6 ntiles
  const int m0 = mt * 256, n0 = nt * 256;

  const int tid = threadIdx.x;
  const int wid = tid >> 6, lane = tid & 63;
  const int wm2 = wid >> 2, wn4 = wid & 3;   // wave -> (M half, N quarter)
  const int l15 = lane & 15, qg = lane >> 4;
  const int hb = wn4 >> 1, rbB = (wn4 & 1) * 64;

  if (tid < 256) srw[tid] = rw[(size_t)(m0 + tid) * NE + e];

  // ds_read offsets (in shorts); col = (ksub*32 + qg*8) ^ ((row&7)<<3)
  const int aoff0 = l15 * 64 + ((qg * 8) ^ ((l15 & 7) << 3));
  const int aoff1 = l15 * 64 + (((32 + qg * 8)) ^ ((l15 & 7) << 3));

  // staging: thread covers chunks tid and tid+512 of a 16KB half-tile
  // chunk ch -> row ch>>3, cpos ch&7; source col-chunk = cpos ^ (row&7)
  const int r8 = tid >> 3;                       // 0..63 (second chunk: +64)
  const int csrc = ((tid & 7) ^ (r8 & 7)) * 8;   // elems
  const unsigned short* w1e = w1t + (size_t)e * NF2 * ND;
  const unsigned short* aSrc = xb  + (size_t)(m0 + r8) * ND + csrc;
  const unsigned short* bSrc = w1e + (size_t)(n0 + r8) * ND + csrc;

#define STAGE_A(buf, h, kt) do {                                              \
    const unsigned short* _g = aSrc + (size_t)(h) * 128 * ND + (size_t)(kt) * 64; \
    GLOAD_LDS16(_g, &sA[buf][h][wid * 512]);                                  \
    GLOAD_LDS16(_g + (size_t)64 * ND, &sA[buf][h][wid * 512 + 4096]);         \
  } while (0)
#define STAGE_B(buf, h, kt) do {                                              \
    const unsigned short* _g = bSrc + (size_t)(h) * 128 * ND + (size_t)(kt) * 64; \
    GLOAD_LDS16(_g, &sB[buf][h][wid * 512]);                                  \
    GLOAD_LDS16(_g + (size_t)64 * ND, &sB[buf][h][wid * 512 + 4096]);         \
  } while (0)

#define DS_A(buf, q) {                                                        \
    a0s0 = *(const short8*)&sA[buf][wm2][((q) * 32 +  0) * 64 + aoff0];       \
    a0s1 = *(const short8*)&sA[buf][wm2][((q) * 32 +  0) * 64 + aoff1];       \
    a1s0 = *(const short8*)&sA[buf][wm2][((q) * 32 + 16) * 64 + aoff0];       \
    a1s1 = *(const short8*)&sA[buf][wm2][((q) * 32 + 16) * 64 + aoff1];       \
  }
#define DS_B(buf) {                                                           \
    b0s0 = *(const short8*)&sB[buf][hb][(rbB +  0) * 64 + aoff0];             \
    b0s1 = *(const short8*)&sB[buf][hb][(rbB +  0) * 64 + aoff1];             \
    b1s0 = *(const short8*)&sB[buf][hb][(rbB + 16) * 64 + aoff0];             \
    b1s1 = *(const short8*)&sB[buf][hb][(rbB + 16) * 64 + aoff1];             \
    b2s0 = *(const short8*)&sB[buf][hb][(rbB + 32) * 64 + aoff0];             \
    b2s1 = *(const short8*)&sB[buf][hb][(rbB + 32) * 64 + aoff1];             \
    b3s0 = *(const short8*)&sB[buf][hb][(rbB + 48) * 64 + aoff0];             \
    b3s1 = *(const short8*)&sB[buf][hb][(rbB + 48) * 64 + aoff1];             \
  }
#define MM(q) do {                                                            \
    __builtin_amdgcn_s_setprio(1);                                            \
    acc[(q)*2+0][0] = MF(a0s0, b0s0, acc[(q)*2+0][0]);                        \
    acc[(q)*2+0][0] = MF(a0s1, b0s1, acc[(q)*2+0][0]);                        \
    acc[(q)*2+0][1] = MF(a0s0, b1s0, acc[(q)*2+0][1]);                        \
    acc[(q)*2+0][1] = MF(a0s1, b1s1, acc[(q)*2+0][1]);                        \
    acc[(q)*2+0][2] = MF(a0s0, b2s0, acc[(q)*2+0][2]);                        \
    acc[(q)*2+0][2] = MF(a0s1, b2s1, acc[(q)*2+0][2]);                        \
    acc[(q)*2+0][3] = MF(a0s0, b3s0, acc[(q)*2+0][3]);                        \
    acc[(q)*2+0][3] = MF(a0s1, b3s1, acc[(q)*2+0][3]);                        \
    acc[(q)*2+1][0] = MF(a1s0, b0s0, acc[(q)*2+1][0]);                        \
    acc[(q)*2+1][0] = MF(a1s1, b0s1, acc[(q)*2+1][0]);                        \
    acc[(q)*2+1][1] = MF(a1s0, b1s0, acc[(q)*2+1][1]);                        \
    acc[(q)*2+1][1] = MF(a1s1, b1s1, acc[(q)*2+1][1]);                        \
    acc[(q)*2+1][2] = MF(a1s0, b2s0, acc[(q)*2+1][2]);                        \
    acc[(q)*2+1][2] = MF(a1s1, b2s1, acc[(q)*2+1][2]);                        \
    acc[(q)*2+1][3] = MF(a1s0, b3s0, acc[(q)*2+1][3]);                        \
    acc[(q)*2+1][3] = MF(a1s1, b3s1, acc[(q)*2+1][3]);                        \
    __builtin_amdgcn_s_setprio(0);                                            \
  } while (0)

#define BAR_OPEN  asm volatile("s_barrier" ::: "memory")
#define BAR_CLOSE asm volatile("s_waitcnt lgkmcnt(0)\n\ts_barrier" ::: "memory")
#define VM4 asm volatile("s_waitcnt vmcnt(4)" ::: "memory")
#define VM0 asm volatile("s_waitcnt vmcnt(0)" ::: "memory")
#define S23_ON(x) x
#define S23_OFF(x)

// One iteration = 2 K-tiles (even->buf0, odd->buf1), 8 phases.
// Stage plan: ph1-2 A(buf1,t1); ph3-4 B(buf0,t2); ph5-6 A(buf0,t2);
// ph7-8 B(buf1,t3).  vmcnt(4) at ph4/ph8 => everything older than the last
// two stage-phases has landed before it is read.
#define KITER(t1, t2, t3, S23, VMT)                                           \
  DS_A(0, 0) DS_B(0) STAGE_A(1, 0, t1); BAR_OPEN; MM(0); BAR_CLOSE;           \
  DS_A(0, 1) STAGE_A(1, 1, t1); BAR_OPEN; MM(1); BAR_CLOSE;                   \
  DS_A(0, 2) S23(STAGE_B(0, 0, t2);) BAR_OPEN; MM(2); BAR_CLOSE;              \
  DS_A(0, 3) S23(STAGE_B(0, 1, t2);) VMT; BAR_OPEN; MM(3); BAR_CLOSE;         \
  DS_A(1, 0) DS_B(1) S23(STAGE_A(0, 0, t2);) BAR_OPEN; MM(0); BAR_CLOSE;      \
  DS_A(1, 1) S23(STAGE_A(0, 1, t2);) BAR_OPEN; MM(1); BAR_CLOSE;              \
  DS_A(1, 2) S23(STAGE_B(1, 0, t3);) BAR_OPEN; MM(2); BAR_CLOSE;              \
  DS_A(1, 3) S23(STAGE_B(1, 1, t3);) VMT; BAR_OPEN; MM(3); BAR_CLOSE;

  short8 a0s0, a0s1, a1s0, a1s1;
  short8 b0s0, b0s1, b1s0, b1s1, b2s0, b2s1, b3s0, b3s1;
  floatx4 acc[8][4];
#pragma unroll
  for (int i = 0; i < 8; i++)
#pragma unroll
    for (int j = 0; j < 4; j++) acc[i][j] = (floatx4){0.f, 0.f, 0.f, 0.f};

  // Prologue: tile0 -> buf0 (B then A), B of tile1 -> buf1; wait tile0 landed.
  STAGE_B(0, 0, 0); STAGE_B(0, 1, 0);
  STAGE_A(0, 0, 0); STAGE_A(0, 1, 0);
  STAGE_B(1, 0, 1); STAGE_B(1, 1, 1);
  VM4; BAR_OPEN;

  const int nI = ND / 64 / 2;   // 16
  for (int i = 0; i < nI - 1; ++i) {
    const int t1 = 2 * i + 1, t2 = 2 * i + 2, t3 = 2 * i + 3;
    KITER(t1, t2, t3, S23_ON, VM4)
  }
  {  // peeled last iteration: no t2/t3 stages; drain at ph4 so ph5 sees A(buf1)
    const int t1 = ND / 64 - 1;
    KITER(t1, 0, 0, S23_OFF, VM0)
  }

  // Epilogue: wave's N-frags 0,1 = gate; 2,3 = matching up (pair-permuted w1t)
  const size_t cb = (size_t)e * NF + (size_t)nt * 128 + wn4 * 32 + l15;
#pragma unroll
  for (int mf = 0; mf < 8; ++mf) {
    const int rbase = wm2 * 128 + mf * 16 + qg * 4;
#pragma unroll
    for (int nf = 0; nf < 2; ++nf)
#pragma unroll
      for (int r = 0; r < 4; ++r) {
        float g = acc[mf][nf][r];
        float u = acc[mf][nf + 2][r];
        float sig = __builtin_amdgcn_rcpf(1.f + __expf(-g));
        float val = u * g * sig * srw[rbase + r];
        gws[(size_t)(m0 + rbase + r) * NEF + cb + nf * 16] = bf16_1(val);
      }
  }
#undef STAGE_A
#undef STAGE_B
#undef DS_A
#undef DS_B
#undef MM
#undef KITER
}

// ---------------------- gemm1 2-phase (slab fallback path) ----------------
__global__ __launch_bounds__(256, 3) void k_gemm1b(
    const unsigned short* __restrict__ xb,   // NT x ND bf16
    const unsigned short* __restrict__ w1t,  // nE x NF2 x ND bf16
    const float* __restrict__ rw,            // NT x NE fp32
    unsigned short* __restrict__ gws,        // NT x NEF bf16
    int e0)
{
  __shared__ unsigned short sA[BM * BK];   // [m][k], 64B rows
  __shared__ unsigned short sG[BN * BK];   // [n][k]
  __shared__ unsigned short sU[BN * BK];
  __shared__ float srw[BM];

  const int el  = blockIdx.y;             // local expert
  const int e   = e0 + el;
  const int mt  = blockIdx.x & 15;
  const int nt  = blockIdx.x >> 4;
  const int m0  = mt * BM, n0 = nt * BN;
  const int tid = threadIdx.x;
  const int wid = tid >> 6, lane = tid & 63;
  const int wm = wid >> 1, wn = wid & 1;
  const int l15 = lane & 15, q = lane >> 4;

  if (tid < BM) srw[tid] = rw[(size_t)(m0 + tid) * NE + e];

  floatx4 accG[4][2], accU[4][2];
#pragma unroll
  for (int i = 0; i < 4; i++)
#pragma unroll
    for (int j = 0; j < 2; j++) {
      accG[i][j] = (floatx4){0.f, 0.f, 0.f, 0.f};
      accU[i][j] = (floatx4){0.f, 0.f, 0.f, 0.f};
    }

  const unsigned short* w1e = w1t + (size_t)el * NF2 * ND;

  const int koff = (lane & 3) * 8;
  const unsigned short* aptr = xb + (size_t)(m0 + wid * 32 + (lane >> 2)) * ND + koff;
  unsigned short* aLds = &sA[wid * 32 * BK];
  const unsigned short* gptr = w1e + (size_t)(n0 + wid * 16 + (lane >> 2)) * ND + koff;
  const unsigned short* uptr = gptr + (size_t)NF * ND;
  unsigned short* gLds = &sG[wid * 16 * BK];
  unsigned short* uLds = &sU[wid * 16 * BK];

  for (int kb = 0; kb < ND / BK; ++kb) {
    __syncthreads();
    GLOAD_LDS16(aptr + kb * BK, aLds);
    GLOAD_LDS16(aptr + kb * BK + 16 * ND, aLds + 16 * BK);
    GLOAD_LDS16(gptr + kb * BK, gLds);
    GLOAD_LDS16(uptr + kb * BK, uLds);
    __syncthreads();

    short8 bg0 = *(const short8*)&sG[(wn * 32 + 0  + l15) * BK + q * 8];
    short8 bg1 = *(const short8*)&sG[(wn * 32 + 16 + l15) * BK + q * 8];
    short8 bu0 = *(const short8*)&sU[(wn * 32 + 0  + l15) * BK + q * 8];
    short8 bu1 = *(const short8*)&sU[(wn * 32 + 16 + l15) * BK + q * 8];
#pragma unroll
    for (int i = 0; i < 4; i++) {
      short8 af = *(const short8*)&sA[(wm * 64 + i * 16 + l15) * BK + q * 8];
      accG[i][0] = MF(af, bg0, accG[i][0]);
      accG[i][1] = MF(af, bg1, accG[i][1]);
      accU[i][0] = MF(af, bu0, accU[i][0]);
      accU[i][1] = MF(af, bu1, accU[i][1]);
    }
  }

  const size_t obase = (size_t)m0 * NEF + (size_t)e * NF + n0 + wn * 32;
#pragma unroll
  for (int i = 0; i < 4; i++)
#pragma unroll
    for (int j = 0; j < 2; j++)
#pragma unroll
      for (int r = 0; r < 4; r++) {
        int row = wm * 64 + i * 16 + q * 4 + r;
        float g = accG[i][j][r];
        float u = accU[i][j][r];
        float sig = __builtin_amdgcn_rcpf(1.f + __expf(-g));
        float val = u * g * sig * srw[row];
        gws[obase + (size_t)row * NEF + j * 16 + l15] = bf16_1(val);
      }
}

// ---------------------- Phase B: gated' @ W2t -> out (atomic) --------------
template<int KSTRIDE, int HITERS>
__global__ __launch_bounds__(256, 3) void k_gemm2b(
    const unsigned short* __restrict__ gb,   // NT x NEF bf16
    const unsigned short* __restrict__ w2t,  // ND x KSTRIDE bf16
    float* __restrict__ out,                 // NT x ND fp32 (pre-zeroed)
    int kbase)
{
  __shared__ unsigned short sA[BM * BK];
  __shared__ unsigned short sB[BN * BK];

  const int mt = blockIdx.x & 15;
  const int nt = blockIdx.x >> 4;
  const int m0 = mt * BM, n0 = nt * BN;
  const int tid = threadIdx.x;
  const int wid = tid >> 6, lane = tid & 63;
  const int wm = wid >> 1, wn = wid & 1;
  const int l15 = lane & 15, q = lane >> 4;

  const int kb0 = blockIdx.y * HITERS;
  const int kb1 = kb0 + HITERS;

  floatx4 acc[4][2];
#pragma unroll
  for (int i = 0; i < 4; i++)
#pragma unroll
    for (int j = 0; j < 2; j++) acc[i][j] = (floatx4){0.f, 0.f, 0.f, 0.f};

  const int koff = (lane & 3) * 8;
  const unsigned short* aptr = gb + (size_t)(m0 + wid * 32 + (lane >> 2)) * NEF + kbase + koff;
  unsigned short* aLds = &sA[wid * 32 * BK];
  const unsigned short* bptr = w2t + (size_t)(n0 + wid * 16 + (lane >> 2)) * KSTRIDE + koff;
  unsigned short* bLds = &sB[wid * 16 * BK];

  for (int kb = kb0; kb < kb1; ++kb) {
    __syncthreads();
    GLOAD_LDS16(aptr + kb * BK, aLds);
    GLOAD_LDS16(aptr + kb * BK + 16 * NEF, aLds + 16 * BK);
    GLOAD_LDS16(bptr + kb * BK, bLds);
    __syncthreads();

    short8 b0 = *(const short8*)&sB[(wn * 32 + 0  + l15) * BK + q * 8];
    short8 b1 = *(const short8*)&sB[(wn * 32 + 16 + l15) * BK + q * 8];
#pragma unroll
    for (int i = 0; i < 4; i++) {
      short8 af = *(const short8*)&sA[(wm * 64 + i * 16 + l15) * BK + q * 8];
      acc[i][0] = MF(af, b0, acc[i][0]);
      acc[i][1] = MF(af, b1, acc[i][1]);
    }
  }

#pragma unroll
  for (int i = 0; i < 4; i++)
#pragma unroll
    for (int j = 0; j < 2; j++)
#pragma unroll
      for (int r = 0; r < 4; r++) {
        int row = wm * 64 + i * 16 + q * 4 + r;
        unsafeAtomicAdd(&out[(size_t)(m0 + row) * ND + n0 + wn * 32 + j * 16 + l15],
                        acc[i][j][r]);
      }
}

// ======================= legacy fp32-weight path (ws fallback) =============
__global__ __launch_bounds__(256, 2) void k_gemm1_legacy(
    const unsigned short* __restrict__ xb, const float* __restrict__ w1,
    const float* __restrict__ rw, unsigned short* __restrict__ gws)
{
  __shared__ unsigned short sA[BM * BK];
  __shared__ unsigned short sG[BN * BSTR];
  __shared__ unsigned short sU[BN * BSTR];
  __shared__ float srw[BM];
  const int e = blockIdx.y, mt = blockIdx.x & 15, nt = blockIdx.x >> 4;
  const int m0 = mt * BM, n0 = nt * BN;
  const int tid = threadIdx.x, wid = tid >> 6, lane = tid & 63;
  const int wm = wid >> 1, wn = wid & 1, l15 = lane & 15, q = lane >> 4;
  if (tid < BM) srw[tid] = rw[(size_t)(m0 + tid) * NE + e];
  const float* w1e = w1 + (size_t)e * ND * (2 * NF);
  floatx4 accG[4][2], accU[4][2];
#pragma unroll
  for (int i = 0; i < 4; i++)
#pragma unroll
    for (int j = 0; j < 2; j++) {
      accG[i][j] = (floatx4){0.f, 0.f, 0.f, 0.f};
      accU[i][j] = (floatx4){0.f, 0.f, 0.f, 0.f};
    }
  const int arow = wid * 32 + (lane >> 2), akoff = (lane & 3) * 8;
  const unsigned short* aptr = xb + (size_t)(m0 + arow) * ND + akoff;
  unsigned short* aLds = &sA[wid * 32 * BK];
  const float* gptr0 = w1e + (size_t)(wid * 8) * (2 * NF) + n0 + lane;
  for (int kb = 0; kb < ND / BK; ++kb) {
    const float* gp = gptr0 + (size_t)kb * BK * (2 * NF);
    float gv[8], uv[8];
#pragma unroll
    for (int r = 0; r < 8; r++) {
      gv[r] = gp[(size_t)r * (2 * NF)];
      uv[r] = gp[(size_t)r * (2 * NF) + NF];
    }
    __syncthreads();
    GLOAD_LDS16(aptr + kb * BK, aLds);
    GLOAD_LDS16(aptr + kb * BK + 16 * ND, aLds + 16 * BK);
    uint4 wg, wu;
    wg.x = pk_bf16(gv[0], gv[1]); wg.y = pk_bf16(gv[2], gv[3]);
    wg.z = pk_bf16(gv[4], gv[5]); wg.w = pk_bf16(gv[6], gv[7]);
    wu.x = pk_bf16(uv[0], uv[1]); wu.y = pk_bf16(uv[2], uv[3]);
    wu.z = pk_bf16(uv[4], uv[5]); wu.w = pk_bf16(uv[6], uv[7]);
    *((uint4*)&sG[lane * BSTR + wid * 8]) = wg;
    *((uint4*)&sU[lane * BSTR + wid * 8]) = wu;
    __syncthreads();
    short8 bg0 = *(const short8*)&sG[(wn * 32 + 0  + l15) * BSTR + q * 8];
    short8 bg1 = *(const short8*)&sG[(wn * 32 + 16 + l15) * BSTR + q * 8];
    short8 bu0 = *(const short8*)&sU[(wn * 32 + 0  + l15) * BSTR + q * 8];
    short8 bu1 = *(const short8*)&sU[(wn * 32 + 16 + l15) * BSTR + q * 8];
#pragma unroll
    for (int i = 0; i < 4; i++) {
      short8 af = *(const short8*)&sA[(wm * 64 + i * 16 + l15) * BK + q * 8];
      accG[i][0] = MF(af, bg0, accG[i][0]);
      accG[i][1] = MF(af, bg1, accG[i][1]);
      accU[i][0] = MF(af, bu0, accU[i][0]);
      accU[i][1] = MF(af, bu1, accU[i][1]);
    }
  }
  const size_t obase = (size_t)m0 * NEF + (size_t)e * NF + n0 + wn * 32;
#pragma unroll
  for (int i = 0; i < 4; i++)
#pragma unroll
    for (int j = 0; j < 2; j++)
#pragma unroll
      for (int r = 0; r < 4; r++) {
        int row = wm * 64 + i * 16 + q * 4 + r;
        float g = accG[i][j][r], u = accU[i][j][r];
        float sig = __builtin_amdgcn_rcpf(1.f + __expf(-g));
        gws[obase + (size_t)row * NEF + j * 16 + l15] = bf16_1(u * g * sig * srw[row]);
      }
}

__global__ __launch_bounds__(256, 2) void k_gemm2_legacy(
    const unsigned short* __restrict__ gb, const float* __restrict__ w2,
    float* __restrict__ out)
{
  __shared__ unsigned short sA[BM * BK];
  __shared__ unsigned short sB[BN * BSTR];
  const int mt = blockIdx.x & 15, nt = blockIdx.x >> 4;
  const int m0 = mt * BM, n0 = nt * BN;
  const int tid = threadIdx.x, wid = tid >> 6, lane = tid & 63;
  const int wm = wid >> 1, wn = wid & 1, l15 = lane & 15, q = lane >> 4;
  const int kb0 = blockIdx.y * (NEF / BK / 4), kb1 = kb0 + (NEF / BK / 4);
  floatx4 acc[4][2];
#pragma unroll
  for (int i = 0; i < 4; i++)
#pragma unroll
    for (int j = 0; j < 2; j++) acc[i][j] = (floatx4){0.f, 0.f, 0.f, 0.f};
  const int arow = wid * 32 + (lane >> 2), akoff = (lane & 3) * 8;
  const unsigned short* aptr = gb + (size_t)(m0 + arow) * NEF + akoff;
  unsigned short* aLds = &sA[wid * 32 * BK];
  const float* bptr0 = w2 + (size_t)(wid * 8) * ND + n0 + lane;
  for (int kb = kb0; kb < kb1; ++kb) {
    const float* bp = bptr0 + (size_t)kb * BK * ND;
    float bv[8];
#pragma unroll
    for (int r = 0; r < 8; r++) bv[r] = bp[(size_t)r * ND];
    __syncthreads();
    GLOAD_LDS16(aptr + kb * BK, aLds);
    GLOAD_LDS16(aptr + kb * BK + 16 * NEF, aLds + 16 * BK);
    uint4 wb;
    wb.x = pk_bf16(bv[0], bv[1]); wb.y = pk_bf16(bv[2], bv[3]);
    wb.z = pk_bf16(bv[4], bv[5]); wb.w = pk_bf16(bv[6], bv[7]);
    *((uint4*)&sB[lane * BSTR + wid * 8]) = wb;
    __syncthreads();
    short8 b0 = *(const short8*)&sB[(wn * 32 + 0  + l15) * BSTR + q * 8];
    short8 b1 = *(const short8*)&sB[(wn * 32 + 16 + l15) * BSTR + q * 8];
#pragma unroll
    for (int i = 0; i < 4; i++) {
      short8 af = *(const short8*)&sA[(wm * 64 + i * 16 + l15) * BK + q * 8];
      acc[i][0] = MF(af, b0, acc[i][0]);
      acc[i][1] = MF(af, b1, acc[i][1]);
    }
  }
#pragma unroll
  for (int i = 0; i < 4; i++)
#pragma unroll
    for (int j = 0; j < 2; j++)
#pragma unroll
      for (int r = 0; r < 4; r++) {
        int row = wm * 64 + i * 16 + q * 4 + r;
        unsafeAtomicAdd(&out[(size_t)(m0 + row) * ND + n0 + wn * 32 + j * 16 + l15],
                        acc[i][j][r]);
      }
}

// ---------------------------------------------------------------------------
extern "C" void kernel_launch(void* const* d_in, const int* in_sizes, int n_in,
                              void* d_out, int out_size, void* d_ws, size_t ws_size,
                              hipStream_t stream) {
  const float* x  = (const float*)d_in[0];   // hidden_states (T,D)
  const float* rw = (const float*)d_in[1];   // routing_weights (T,E)
  // d_in[2] router_indices: unused by reference
  const float* w1 = (const float*)d_in[3];   // gate_up_proj (E,D,2F)
  const float* w2 = (const float*)d_in[4];   // down_proj (E,F,D)
  float* out = (float*)d_out;

  // ws layouts:
  //  full: [xb 8MB][gb 100.7MB][w1t 201.3MB][w2t 100.7MB] = 411 MB
  //  slab: [xb 8MB][gb 100.7MB][wtb 50.3MB]               = 159.4 MB
  unsigned short* xb  = (unsigned short*)d_ws;
  unsigned short* gb  = xb + (size_t)NT * ND;
  unsigned short* wtb = gb + (size_t)NT * NEF;
  unsigned short* w1t = wtb;
  unsigned short* w2t = w1t + (size_t)NE * NF2 * ND;
  const size_t WS_FULL = ((size_t)NT * ND + (size_t)NT * NEF +
                          (size_t)NE * NF2 * ND + (size_t)ND * NEF) * 2;  // 411 MB
  const size_t WS_NEED = ((size_t)NT * ND + (size_t)NT * NEF +
                          (size_t)8 * NF2 * ND) * 2;  // 159.4 MB

  hipMemsetAsync(out, 0, (size_t)out_size * sizeof(float), stream);
  k_cvt_x<<<(NT * ND / 4 + 255) / 256, 256, 0, stream>>>(x, xb, NT * ND / 4);

  if (ws_size >= WS_FULL) {
    // -------- full path: 8-phase gemm1, all weights transposed up front
    {
      dim3 gt(NF2 / 64, ND / 64, NE);   // 24 x 32 x 32 -- W1 (pair-permuted)
      k_trans<1><<<gt, 256, 0, stream>>>(w1, w1t, ND, NF2, (size_t)ND * NF2);
    }
    {
      dim3 gt(ND / 64, NEF / 64, 1);    // 32 x 384 -- W2
      k_trans<0><<<gt, 256, 0, stream>>>(w2, w2t, NEF, ND, 0);
    }
    k_gemm1p<<<dim3(8 * 6 * NE), 512, 0, stream>>>(xb, w1t, rw, gb);
    {
      dim3 g2(16 * (ND / BN), 2);       // 512 x 2, k-split over full NEF
      k_gemm2b<NEF, NEF / BK / 2><<<g2, 256, 0, stream>>>(gb, w2t, out, 0);
    }
  } else if (ws_size >= WS_NEED) {
    // -------- slab path (2-phase structure)
    for (int qc = 0; qc < 4; ++qc) {
      dim3 gt(NF2 / 64, ND / 64, 8);
      k_trans<0><<<gt, 256, 0, stream>>>(w1 + (size_t)qc * 8 * ND * NF2, wtb,
                                         ND, NF2, (size_t)ND * NF2);
      dim3 g1(16 * (NF / BN), 8);
      k_gemm1b<<<g1, 256, 0, stream>>>(xb, wtb, rw, gb, qc * 8);
    }
    for (int h = 0; h < 2; ++h) {
      dim3 gt(ND / 64, KH / 64, 1);
      k_trans<0><<<gt, 256, 0, stream>>>(w2 + (size_t)h * KH * ND, wtb, KH, ND, 0);
      dim3 g2(16 * (ND / BN), 2);
      k_gemm2b<KH, KH / BK / 2><<<g2, 256, 0, stream>>>(gb, wtb, out, h * KH);
    }
  } else {
    // legacy fp32-weight path
    dim3 gA(16 * (NF / BN), NE);
    k_gemm1_legacy<<<gA, 256, 0, stream>>>(xb, w1, rw, gb);
    dim3 gB(16 * (ND / BN), 4);
    k_gemm2_legacy<<<gB, 256, 0, stream>>>(gb, w2, out);
  }
}

// Round 3
// 1326.447 us; speedup vs baseline: 1.1657x; 1.0748x over previous
//
#include <hip/hip_runtime.h>
#include <stdint.h>

// Problem constants (dense MoE: router_indices UNUSED by the reference)
#define NE 32
#define ND 2048
#define NF 768
#define NF2 1536        // 2F
#define NT 2048
#define NEF (NE * NF)   // 24576
#define KH 12288        // W2 K-half (slab path)

// Tile config (2-phase kernels)
#define BM 128
#define BN 64
#define BK 32
#define BSTR 40     // legacy-path LDS B stride

typedef __attribute__((ext_vector_type(8))) short short8;
typedef __attribute__((ext_vector_type(4))) float floatx4;

__device__ __forceinline__ unsigned pk_bf16(float a, float b) {
  union { float f; unsigned u; } ua, ub;
  ua.f = a; ub.f = b;
  unsigned ra = (ua.u + 0x7fffu + ((ua.u >> 16) & 1u)) >> 16;
  unsigned rb = (ub.u + 0x7fffu + ((ub.u >> 16) & 1u)) & 0xffff0000u;
  return ra | rb;
}
__device__ __forceinline__ unsigned short bf16_1(float a) {
  union { float f; unsigned u; } ua; ua.f = a;
  return (unsigned short)((ua.u + 0x7fffu + ((ua.u >> 16) & 1u)) >> 16);
}

#define GLOAD_LDS16(g, l)                                                     \
  __builtin_amdgcn_global_load_lds(                                           \
      (const __attribute__((address_space(1))) void*)(g),                     \
      (__attribute__((address_space(3))) void*)(l), 16, 0, 0)

#define MF(a, b, c) __builtin_amdgcn_mfma_f32_16x16x32_bf16(a, b, c, 0, 0, 0)

// ---------------------------------------------------------------- X -> bf16
__global__ void k_cvt_x(const float* __restrict__ x, unsigned short* __restrict__ xb, int n4) {
  int i = blockIdx.x * blockDim.x + threadIdx.x;
  if (i < n4) {
    float4 v = ((const float4*)x)[i];
    uint2 o;
    o.x = pk_bf16(v.x, v.y);
    o.y = pk_bf16(v.z, v.w);
    ((uint2*)xb)[i] = o;
  }
}

// ------------------------------------ fp32 [R][C] -> bf16 [C][R] transpose
// 64x64 tile, 256 threads. blockIdx.z selects sub-matrix (stride zstride elems
// on both sides). Out row stride == R.
// PAIR=1: permute output rows so each 64-row group = 32 gate rows + the 32
// matching up rows. Used for W1 so gemm1 epilogue pairs gate/up in-register.
template <int PAIR>
__global__ void k_trans(const float* __restrict__ in, unsigned short* __restrict__ out,
                        int R, int C, size_t zstride) {
  __shared__ float sT[64][65];
  in  += (size_t)blockIdx.z * zstride;
  out += (size_t)blockIdx.z * zstride;
  const int r0 = blockIdx.y * 64, c0 = blockIdx.x * 64;
  const int t = threadIdx.x;
  const int lrow = t >> 4, lc4 = (t & 15) * 4;
#pragma unroll
  for (int i = 0; i < 4; i++) {
    float4 v = *(const float4*)&in[(size_t)(r0 + lrow + i * 16) * C + c0 + lc4];
    sT[lrow + i * 16][lc4 + 0] = v.x;
    sT[lrow + i * 16][lc4 + 1] = v.y;
    sT[lrow + i * 16][lc4 + 2] = v.z;
    sT[lrow + i * 16][lc4 + 3] = v.w;
  }
  __syncthreads();
  const int c = t >> 2, rg = (t & 3) * 16;
  uint4 o0, o1;
  o0.x = pk_bf16(sT[rg + 0][c],  sT[rg + 1][c]);
  o0.y = pk_bf16(sT[rg + 2][c],  sT[rg + 3][c]);
  o0.z = pk_bf16(sT[rg + 4][c],  sT[rg + 5][c]);
  o0.w = pk_bf16(sT[rg + 6][c],  sT[rg + 7][c]);
  o1.x = pk_bf16(sT[rg + 8][c],  sT[rg + 9][c]);
  o1.y = pk_bf16(sT[rg + 10][c], sT[rg + 11][c]);
  o1.z = pk_bf16(sT[rg + 12][c], sT[rg + 13][c]);
  o1.w = pk_bf16(sT[rg + 14][c], sT[rg + 15][c]);
  int oc = c0 + c;
  if (PAIR) {
    oc = (oc < NF) ? (((oc >> 5) << 6) + (oc & 31))
                   : ((((oc - NF) >> 5) << 6) + 32 + ((oc - NF) & 31));
  }
  unsigned short* op = &out[(size_t)oc * R + r0 + rg];
  ((uint4*)op)[0] = o0;
  ((uint4*)op)[1] = o1;
}

// ===================== Phase A: 8-phase 256x256xBK64 pipelined GEMM ========
// X @ W1t^T + silu-gate -> gated' (bf16). w1t rows pair-permuted (see k_trans).
// 512 threads = 8 waves (2M x 4N); per-wave C = 128x64; 16 MFMA/phase;
// counted vmcnt(4) at phases 4/8 only; LDS XOR-swizzle (both-sides, rule #21).
__global__ __launch_bounds__(512, 2) void k_gemm1p(
    const unsigned short* __restrict__ xb,   // NT x ND bf16
    const unsigned short* __restrict__ w1t,  // NE x NF2 x ND bf16 (pair-permuted rows)
    const float* __restrict__ rw,            // NT x NE fp32
    unsigned short* __restrict__ gws)        // NT x NEF bf16
{
  __shared__ unsigned short sA[2][2][8192];  // [buf][half][128*64]
  __shared__ unsigned short sB[2][2][8192];
  __shared__ float srw[256];

  // XCD-aware bijective swizzle (nwg = 1536, %8 == 0)
  const int bx = blockIdx.x;
  const int L  = (bx & 7) * 192 + (bx >> 3);
  const int e  = L / 48;
  const int rem = L - e * 48;
  const int mt = rem & 7, nt = rem >> 3;     // 8 mtiles x 6 ntiles
  const int m0 = mt * 256, n0 = nt * 256;

  const int tid = threadIdx.x;
  const int wid = tid >> 6, lane = tid & 63;
  const int wm2 = wid >> 2, wn4 = wid & 3;   // wave -> (M half, N quarter)
  const int l15 = lane & 15, qg = lane >> 4;
  const int hb = wn4 >> 1, rbB = (wn4 & 1) * 64;

  if (tid < 256) srw[tid] = rw[(size_t)(m0 + tid) * NE + e];

  // ds_read offsets (in shorts); col = (ksub*32 + qg*8) ^ ((row&7)<<3)
  const int aoff0 = l15 * 64 + ((qg * 8) ^ ((l15 & 7) << 3));
  const int aoff1 = l15 * 64 + (((32 + qg * 8)) ^ ((l15 & 7) << 3));

  // staging: thread covers chunks tid and tid+512 of a 16KB half-tile
  // chunk ch -> row ch>>3, cpos ch&7; source col-chunk = cpos ^ (row&7)
  const int r8 = tid >> 3;                       // 0..63 (second chunk: +64)
  const int csrc = ((tid & 7) ^ (r8 & 7)) * 8;   // elems
  const unsigned short* w1e = w1t + (size_t)e * NF2 * ND;
  const unsigned short* aSrc = xb  + (size_t)(m0 + r8) * ND + csrc;
  const unsigned short* bSrc = w1e + (size_t)(n0 + r8) * ND + csrc;

#define STAGE_A(buf, h, kt) do {                                              \
    const unsigned short* _g = aSrc + (size_t)(h) * 128 * ND + (size_t)(kt) * 64; \
    GLOAD_LDS16(_g, &sA[buf][h][wid * 512]);                                  \
    GLOAD_LDS16(_g + (size_t)64 * ND, &sA[buf][h][wid * 512 + 4096]);         \
  } while (0)
#define STAGE_B(buf, h, kt) do {                                              \
    const unsigned short* _g = bSrc + (size_t)(h) * 128 * ND + (size_t)(kt) * 64; \
    GLOAD_LDS16(_g, &sB[buf][h][wid * 512]);                                  \
    GLOAD_LDS16(_g + (size_t)64 * ND, &sB[buf][h][wid * 512 + 4096]);         \
  } while (0)

#define DS_A(buf, q) {                                                        \
    a0s0 = *(const short8*)&sA[buf][wm2][((q) * 32 +  0) * 64 + aoff0];       \
    a0s1 = *(const short8*)&sA[buf][wm2][((q) * 32 +  0) * 64 + aoff1];       \
    a1s0 = *(const short8*)&sA[buf][wm2][((q) * 32 + 16) * 64 + aoff0];       \
    a1s1 = *(const short8*)&sA[buf][wm2][((q) * 32 + 16) * 64 + aoff1];       \
  }
#define DS_B(buf) {                                                           \
    b0s0 = *(const short8*)&sB[buf][hb][(rbB +  0) * 64 + aoff0];             \
    b0s1 = *(const short8*)&sB[buf][hb][(rbB +  0) * 64 + aoff1];             \
    b1s0 = *(const short8*)&sB[buf][hb][(rbB + 16) * 64 + aoff0];             \
    b1s1 = *(const short8*)&sB[buf][hb][(rbB + 16) * 64 + aoff1];             \
    b2s0 = *(const short8*)&sB[buf][hb][(rbB + 32) * 64 + aoff0];             \
    b2s1 = *(const short8*)&sB[buf][hb][(rbB + 32) * 64 + aoff1];             \
    b3s0 = *(const short8*)&sB[buf][hb][(rbB + 48) * 64 + aoff0];             \
    b3s1 = *(const short8*)&sB[buf][hb][(rbB + 48) * 64 + aoff1];             \
  }
#define MM(q) do {                                                            \
    __builtin_amdgcn_s_setprio(1);                                            \
    acc[(q)*2+0][0] = MF(a0s0, b0s0, acc[(q)*2+0][0]);                        \
    acc[(q)*2+0][0] = MF(a0s1, b0s1, acc[(q)*2+0][0]);                        \
    acc[(q)*2+0][1] = MF(a0s0, b1s0, acc[(q)*2+0][1]);                        \
    acc[(q)*2+0][1] = MF(a0s1, b1s1, acc[(q)*2+0][1]);                        \
    acc[(q)*2+0][2] = MF(a0s0, b2s0, acc[(q)*2+0][2]);                        \
    acc[(q)*2+0][2] = MF(a0s1, b2s1, acc[(q)*2+0][2]);                        \
    acc[(q)*2+0][3] = MF(a0s0, b3s0, acc[(q)*2+0][3]);                        \
    acc[(q)*2+0][3] = MF(a0s1, b3s1, acc[(q)*2+0][3]);                        \
    acc[(q)*2+1][0] = MF(a1s0, b0s0, acc[(q)*2+1][0]);                        \
    acc[(q)*2+1][0] = MF(a1s1, b0s1, acc[(q)*2+1][0]);                        \
    acc[(q)*2+1][1] = MF(a1s0, b1s0, acc[(q)*2+1][1]);                        \
    acc[(q)*2+1][1] = MF(a1s1, b1s1, acc[(q)*2+1][1]);                        \
    acc[(q)*2+1][2] = MF(a1s0, b2s0, acc[(q)*2+1][2]);                        \
    acc[(q)*2+1][2] = MF(a1s1, b2s1, acc[(q)*2+1][2]);                        \
    acc[(q)*2+1][3] = MF(a1s0, b3s0, acc[(q)*2+1][3]);                        \
    acc[(q)*2+1][3] = MF(a1s1, b3s1, acc[(q)*2+1][3]);                        \
    __builtin_amdgcn_s_setprio(0);                                            \
  } while (0)

#define BAR_OPEN  asm volatile("s_barrier" ::: "memory")
#define BAR_CLOSE asm volatile("s_waitcnt lgkmcnt(0)\n\ts_barrier" ::: "memory")
#define VM4 asm volatile("s_waitcnt vmcnt(4)" ::: "memory")
#define VM0 asm volatile("s_waitcnt vmcnt(0)" ::: "memory")
#define S23_ON(x) x
#define S23_OFF(x)

// One iteration = 2 K-tiles (even->buf0, odd->buf1), 8 phases.
// Stage plan: ph1-2 A(buf1,t1); ph3-4 B(buf0,t2); ph5-6 A(buf0,t2);
// ph7-8 B(buf1,t3).  vmcnt(4) at ph4/ph8 => everything older than the last
// two stage-phases has landed before it is read.
#define KITER(t1, t2, t3, S23, VMT)                                           \
  DS_A(0, 0) DS_B(0) STAGE_A(1, 0, t1); BAR_OPEN; MM(0); BAR_CLOSE;           \
  DS_A(0, 1) STAGE_A(1, 1, t1); BAR_OPEN; MM(1); BAR_CLOSE;                   \
  DS_A(0, 2) S23(STAGE_B(0, 0, t2);) BAR_OPEN; MM(2); BAR_CLOSE;              \
  DS_A(0, 3) S23(STAGE_B(0, 1, t2);) VMT; BAR_OPEN; MM(3); BAR_CLOSE;         \
  DS_A(1, 0) DS_B(1) S23(STAGE_A(0, 0, t2);) BAR_OPEN; MM(0); BAR_CLOSE;      \
  DS_A(1, 1) S23(STAGE_A(0, 1, t2);) BAR_OPEN; MM(1); BAR_CLOSE;              \
  DS_A(1, 2) S23(STAGE_B(1, 0, t3);) BAR_OPEN; MM(2); BAR_CLOSE;              \
  DS_A(1, 3) S23(STAGE_B(1, 1, t3);) VMT; BAR_OPEN; MM(3); BAR_CLOSE;

  short8 a0s0, a0s1, a1s0, a1s1;
  short8 b0s0, b0s1, b1s0, b1s1, b2s0, b2s1, b3s0, b3s1;
  floatx4 acc[8][4];
#pragma unroll
  for (int i = 0; i < 8; i++)
#pragma unroll
    for (int j = 0; j < 4; j++) acc[i][j] = (floatx4){0.f, 0.f, 0.f, 0.f};

  // Prologue: tile0 -> buf0 (B then A), B of tile1 -> buf1; wait tile0 landed.
  STAGE_B(0, 0, 0); STAGE_B(0, 1, 0);
  STAGE_A(0, 0, 0); STAGE_A(0, 1, 0);
  STAGE_B(1, 0, 1); STAGE_B(1, 1, 1);
  VM4; BAR_OPEN;

  const int nI = ND / 64 / 2;   // 16
  for (int i = 0; i < nI - 1; ++i) {
    const int t1 = 2 * i + 1, t2 = 2 * i + 2, t3 = 2 * i + 3;
    KITER(t1, t2, t3, S23_ON, VM4)
  }
  {  // peeled last iteration: no t2/t3 stages; drain at ph4 so ph5 sees A(buf1)
    const int t1 = ND / 64 - 1;
    KITER(t1, 0, 0, S23_OFF, VM0)
  }

  // Epilogue: wave's N-frags 0,1 = gate; 2,3 = matching up (pair-permuted w1t)
  const size_t cb = (size_t)e * NF + (size_t)nt * 128 + wn4 * 32 + l15;
#pragma unroll
  for (int mf = 0; mf < 8; ++mf) {
    const int rbase = wm2 * 128 + mf * 16 + qg * 4;
#pragma unroll
    for (int nf = 0; nf < 2; ++nf)
#pragma unroll
      for (int r = 0; r < 4; ++r) {
        float g = acc[mf][nf][r];
        float u = acc[mf][nf + 2][r];
        float sig = __builtin_amdgcn_rcpf(1.f + __expf(-g));
        float val = u * g * sig * srw[rbase + r];
        gws[(size_t)(m0 + rbase + r) * NEF + cb + nf * 16] = bf16_1(val);
      }
  }
#undef STAGE_A
#undef STAGE_B
#undef KITER
}

// ===================== Phase B: 8-phase 256x256xBK64 pipelined GEMM ========
// gated' @ W2t^T -> out (fp32 atomic). Same schedule as k_gemm1p.
// grid: 64 tiles x 4 ksplit = 256 blocks (1/CU), K = 6144 per block.
__global__ __launch_bounds__(512, 2) void k_gemm2p(
    const unsigned short* __restrict__ gb,   // NT x NEF bf16
    const unsigned short* __restrict__ w2t,  // ND x NEF bf16
    float* __restrict__ out)                 // NT x ND fp32 (pre-zeroed)
{
  __shared__ unsigned short sA[2][2][8192];
  __shared__ unsigned short sB[2][2][8192];

  // XCD bijective swizzle (nwg = 256, %8 == 0)
  const int bx = blockIdx.x;
  const int L  = (bx & 7) * 32 + (bx >> 3);
  const int ks = L & 3;
  const int tile = L >> 2;                   // 0..63
  const int mt = tile & 7, nt = tile >> 3;
  const int m0 = mt * 256, n0 = nt * 256;

  const int tid = threadIdx.x;
  const int wid = tid >> 6, lane = tid & 63;
  const int wm2 = wid >> 2, wn4 = wid & 3;
  const int l15 = lane & 15, qg = lane >> 4;
  const int hb = wn4 >> 1, rbB = (wn4 & 1) * 64;

  const int aoff0 = l15 * 64 + ((qg * 8) ^ ((l15 & 7) << 3));
  const int aoff1 = l15 * 64 + (((32 + qg * 8)) ^ ((l15 & 7) << 3));

  const int r8 = tid >> 3;
  const int csrc = ((tid & 7) ^ (r8 & 7)) * 8;
  const size_t kb0e = (size_t)ks * (NEF / 4);          // 6144 elems
  const unsigned short* aSrc = gb  + (size_t)(m0 + r8) * NEF + kb0e + csrc;
  const unsigned short* bSrc = w2t + (size_t)(n0 + r8) * NEF + kb0e + csrc;

#define STAGE2_A(buf, h, kt) do {                                             \
    const unsigned short* _g = aSrc + (size_t)(h) * 128 * NEF + (size_t)(kt) * 64; \
    GLOAD_LDS16(_g, &sA[buf][h][wid * 512]);                                  \
    GLOAD_LDS16(_g + (size_t)64 * NEF, &sA[buf][h][wid * 512 + 4096]);        \
  } while (0)
#define STAGE2_B(buf, h, kt) do {                                             \
    const unsigned short* _g = bSrc + (size_t)(h) * 128 * NEF + (size_t)(kt) * 64; \
    GLOAD_LDS16(_g, &sB[buf][h][wid * 512]);                                  \
    GLOAD_LDS16(_g + (size_t)64 * NEF, &sB[buf][h][wid * 512 + 4096]);        \
  } while (0)

#define KITER2(t1, t2, t3, S23, VMT)                                          \
  DS_A(0, 0) DS_B(0) STAGE2_A(1, 0, t1); BAR_OPEN; MM(0); BAR_CLOSE;          \
  DS_A(0, 1) STAGE2_A(1, 1, t1); BAR_OPEN; MM(1); BAR_CLOSE;                  \
  DS_A(0, 2) S23(STAGE2_B(0, 0, t2);) BAR_OPEN; MM(2); BAR_CLOSE;             \
  DS_A(0, 3) S23(STAGE2_B(0, 1, t2);) VMT; BAR_OPEN; MM(3); BAR_CLOSE;        \
  DS_A(1, 0) DS_B(1) S23(STAGE2_A(0, 0, t2);) BAR_OPEN; MM(0); BAR_CLOSE;     \
  DS_A(1, 1) S23(STAGE2_A(0, 1, t2);) BAR_OPEN; MM(1); BAR_CLOSE;             \
  DS_A(1, 2) S23(STAGE2_B(1, 0, t3);) BAR_OPEN; MM(2); BAR_CLOSE;             \
  DS_A(1, 3) S23(STAGE2_B(1, 1, t3);) VMT; BAR_OPEN; MM(3); BAR_CLOSE;

  short8 a0s0, a0s1, a1s0, a1s1;
  short8 b0s0, b0s1, b1s0, b1s1, b2s0, b2s1, b3s0, b3s1;
  floatx4 acc[8][4];
#pragma unroll
  for (int i = 0; i < 8; i++)
#pragma unroll
    for (int j = 0; j < 4; j++) acc[i][j] = (floatx4){0.f, 0.f, 0.f, 0.f};

  // Prologue
  STAGE2_B(0, 0, 0); STAGE2_B(0, 1, 0);
  STAGE2_A(0, 0, 0); STAGE2_A(0, 1, 0);
  STAGE2_B(1, 0, 1); STAGE2_B(1, 1, 1);
  VM4; BAR_OPEN;

  const int nI = (NEF / 4) / 64 / 2;   // 48
  for (int i = 0; i < nI - 1; ++i) {
    const int t1 = 2 * i + 1, t2 = 2 * i + 2, t3 = 2 * i + 3;
    KITER2(t1, t2, t3, S23_ON, VM4)
  }
  {
    const int t1 = (NEF / 4) / 64 - 1;   // 95
    KITER2(t1, 0, 0, S23_OFF, VM0)
  }

  // Epilogue: 128 fp32 atomics per thread into pre-zeroed out
#pragma unroll
  for (int mf = 0; mf < 8; ++mf) {
    const int row = m0 + wm2 * 128 + mf * 16 + qg * 4;
#pragma unroll
    for (int nf = 0; nf < 4; ++nf) {
      const int col = n0 + hb * 128 + rbB + nf * 16 + l15;
#pragma unroll
      for (int r = 0; r < 4; ++r)
        unsafeAtomicAdd(&out[(size_t)(row + r) * ND + col], acc[mf][nf][r]);
    }
  }
#undef STAGE2_A
#undef STAGE2_B
#undef KITER2
#undef DS_A
#undef DS_B
#undef MM
}

// ---------------------- gemm1 2-phase (slab fallback path) ----------------
__global__ __launch_bounds__(256, 3) void k_gemm1b(
    const unsigned short* __restrict__ xb,   // NT x ND bf16
    const unsigned short* __restrict__ w1t,  // nE x NF2 x ND bf16
    const float* __restrict__ rw,            // NT x NE fp32
    unsigned short* __restrict__ gws,        // NT x NEF bf16
    int e0)
{
  __shared__ unsigned short sA[BM * BK];   // [m][k], 64B rows
  __shared__ unsigned short sG[BN * BK];   // [n][k]
  __shared__ unsigned short sU[BN * BK];
  __shared__ float srw[BM];

  const int el  = blockIdx.y;             // local expert
  const int e   = e0 + el;
  const int mt  = blockIdx.x & 15;
  const int nt  = blockIdx.x >> 4;
  const int m0  = mt * BM, n0 = nt * BN;
  const int tid = threadIdx.x;
  const int wid = tid >> 6, lane = tid & 63;
  const int wm = wid >> 1, wn = wid & 1;
  const int l15 = lane & 15, q = lane >> 4;

  if (tid < BM) srw[tid] = rw[(size_t)(m0 + tid) * NE + e];

  floatx4 accG[4][2], accU[4][2];
#pragma unroll
  for (int i = 0; i < 4; i++)
#pragma unroll
    for (int j = 0; j < 2; j++) {
      accG[i][j] = (floatx4){0.f, 0.f, 0.f, 0.f};
      accU[i][j] = (floatx4){0.f, 0.f, 0.f, 0.f};
    }

  const unsigned short* w1e = w1t + (size_t)el * NF2 * ND;

  const int koff = (lane & 3) * 8;
  const unsigned short* aptr = xb + (size_t)(m0 + wid * 32 + (lane >> 2)) * ND + koff;
  unsigned short* aLds = &sA[wid * 32 * BK];
  const unsigned short* gptr = w1e + (size_t)(n0 + wid * 16 + (lane >> 2)) * ND + koff;
  const unsigned short* uptr = gptr + (size_t)NF * ND;
  unsigned short* gLds = &sG[wid * 16 * BK];
  unsigned short* uLds = &sU[wid * 16 * BK];

  for (int kb = 0; kb < ND / BK; ++kb) {
    __syncthreads();
    GLOAD_LDS16(aptr + kb * BK, aLds);
    GLOAD_LDS16(aptr + kb * BK + 16 * ND, aLds + 16 * BK);
    GLOAD_LDS16(gptr + kb * BK, gLds);
    GLOAD_LDS16(uptr + kb * BK, uLds);
    __syncthreads();

    short8 bg0 = *(const short8*)&sG[(wn * 32 + 0  + l15) * BK + q * 8];
    short8 bg1 = *(const short8*)&sG[(wn * 32 + 16 + l15) * BK + q * 8];
    short8 bu0 = *(const short8*)&sU[(wn * 32 + 0  + l15) * BK + q * 8];
    short8 bu1 = *(const short8*)&sU[(wn * 32 + 16 + l15) * BK + q * 8];
#pragma unroll
    for (int i = 0; i < 4; i++) {
      short8 af = *(const short8*)&sA[(wm * 64 + i * 16 + l15) * BK + q * 8];
      accG[i][0] = MF(af, bg0, accG[i][0]);
      accG[i][1] = MF(af, bg1, accG[i][1]);
      accU[i][0] = MF(af, bu0, accU[i][0]);
      accU[i][1] = MF(af, bu1, accU[i][1]);
    }
  }

  const size_t obase = (size_t)m0 * NEF + (size_t)e * NF + n0 + wn * 32;
#pragma unroll
  for (int i = 0; i < 4; i++)
#pragma unroll
    for (int j = 0; j < 2; j++)
#pragma unroll
      for (int r = 0; r < 4; r++) {
        int row = wm * 64 + i * 16 + q * 4 + r;
        float g = accG[i][j][r];
        float u = accU[i][j][r];
        float sig = __builtin_amdgcn_rcpf(1.f + __expf(-g));
        float val = u * g * sig * srw[row];
        gws[obase + (size_t)row * NEF + j * 16 + l15] = bf16_1(val);
      }
}

// ---------------------- gemm2 2-phase (slab fallback path) -----------------
template<int KSTRIDE, int HITERS>
__global__ __launch_bounds__(256, 3) void k_gemm2b(
    const unsigned short* __restrict__ gb,   // NT x NEF bf16
    const unsigned short* __restrict__ w2t,  // ND x KSTRIDE bf16
    float* __restrict__ out,                 // NT x ND fp32 (pre-zeroed)
    int kbase)
{
  __shared__ unsigned short sA[BM * BK];
  __shared__ unsigned short sB[BN * BK];

  const int mt = blockIdx.x & 15;
  const int nt = blockIdx.x >> 4;
  const int m0 = mt * BM, n0 = nt * BN;
  const int tid = threadIdx.x;
  const int wid = tid >> 6, lane = tid & 63;
  const int wm = wid >> 1, wn = wid & 1;
  const int l15 = lane & 15, q = lane >> 4;

  const int kb0 = blockIdx.y * HITERS;
  const int kb1 = kb0 + HITERS;

  floatx4 acc[4][2];
#pragma unroll
  for (int i = 0; i < 4; i++)
#pragma unroll
    for (int j = 0; j < 2; j++) acc[i][j] = (floatx4){0.f, 0.f, 0.f, 0.f};

  const int koff = (lane & 3) * 8;
  const unsigned short* aptr = gb + (size_t)(m0 + wid * 32 + (lane >> 2)) * NEF + kbase + koff;
  unsigned short* aLds = &sA[wid * 32 * BK];
  const unsigned short* bptr = w2t + (size_t)(n0 + wid * 16 + (lane >> 2)) * KSTRIDE + koff;
  unsigned short* bLds = &sB[wid * 16 * BK];

  for (int kb = kb0; kb < kb1; ++kb) {
    __syncthreads();
    GLOAD_LDS16(aptr + kb * BK, aLds);
    GLOAD_LDS16(aptr + kb * BK + 16 * NEF, aLds + 16 * BK);
    GLOAD_LDS16(bptr + kb * BK, bLds);
    __syncthreads();

    short8 b0 = *(const short8*)&sB[(wn * 32 + 0  + l15) * BK + q * 8];
    short8 b1 = *(const short8*)&sB[(wn * 32 + 16 + l15) * BK + q * 8];
#pragma unroll
    for (int i = 0; i < 4; i++) {
      short8 af = *(const short8*)&sA[(wm * 64 + i * 16 + l15) * BK + q * 8];
      acc[i][0] = MF(af, b0, acc[i][0]);
      acc[i][1] = MF(af, b1, acc[i][1]);
    }
  }

#pragma unroll
  for (int i = 0; i < 4; i++)
#pragma unroll
    for (int j = 0; j < 2; j++)
#pragma unroll
      for (int r = 0; r < 4; r++) {
        int row = wm * 64 + i * 16 + q * 4 + r;
        unsafeAtomicAdd(&out[(size_t)(m0 + row) * ND + n0 + wn * 32 + j * 16 + l15],
                        acc[i][j][r]);
      }
}

// ======================= legacy fp32-weight path (ws fallback) =============
__global__ __launch_bounds__(256, 2) void k_gemm1_legacy(
    const unsigned short* __restrict__ xb, const float* __restrict__ w1,
    const float* __restrict__ rw, unsigned short* __restrict__ gws)
{
  __shared__ unsigned short sA[BM * BK];
  __shared__ unsigned short sG[BN * BSTR];
  __shared__ unsigned short sU[BN * BSTR];
  __shared__ float srw[BM];
  const int e = blockIdx.y, mt = blockIdx.x & 15, nt = blockIdx.x >> 4;
  const int m0 = mt * BM, n0 = nt * BN;
  const int tid = threadIdx.x, wid = tid >> 6, lane = tid & 63;
  const int wm = wid >> 1, wn = wid & 1, l15 = lane & 15, q = lane >> 4;
  if (tid < BM) srw[tid] = rw[(size_t)(m0 + tid) * NE + e];
  const float* w1e = w1 + (size_t)e * ND * (2 * NF);
  floatx4 accG[4][2], accU[4][2];
#pragma unroll
  for (int i = 0; i < 4; i++)
#pragma unroll
    for (int j = 0; j < 2; j++) {
      accG[i][j] = (floatx4){0.f, 0.f, 0.f, 0.f};
      accU[i][j] = (floatx4){0.f, 0.f, 0.f, 0.f};
    }
  const int arow = wid * 32 + (lane >> 2), akoff = (lane & 3) * 8;
  const unsigned short* aptr = xb + (size_t)(m0 + arow) * ND + akoff;
  unsigned short* aLds = &sA[wid * 32 * BK];
  const float* gptr0 = w1e + (size_t)(wid * 8) * (2 * NF) + n0 + lane;
  for (int kb = 0; kb < ND / BK; ++kb) {
    const float* gp = gptr0 + (size_t)kb * BK * (2 * NF);
    float gv[8], uv[8];
#pragma unroll
    for (int r = 0; r < 8; r++) {
      gv[r] = gp[(size_t)r * (2 * NF)];
      uv[r] = gp[(size_t)r * (2 * NF) + NF];
    }
    __syncthreads();
    GLOAD_LDS16(aptr + kb * BK, aLds);
    GLOAD_LDS16(aptr + kb * BK + 16 * ND, aLds + 16 * BK);
    uint4 wg, wu;
    wg.x = pk_bf16(gv[0], gv[1]); wg.y = pk_bf16(gv[2], gv[3]);
    wg.z = pk_bf16(gv[4], gv[5]); wg.w = pk_bf16(gv[6], gv[7]);
    wu.x = pk_bf16(uv[0], uv[1]); wu.y = pk_bf16(uv[2], uv[3]);
    wu.z = pk_bf16(uv[4], uv[5]); wu.w = pk_bf16(uv[6], uv[7]);
    *((uint4*)&sG[lane * BSTR + wid * 8]) = wg;
    *((uint4*)&sU[lane * BSTR + wid * 8]) = wu;
    __syncthreads();
    short8 bg0 = *(const short8*)&sG[(wn * 32 + 0  + l15) * BSTR + q * 8];
    short8 bg1 = *(const short8*)&sG[(wn * 32 + 16 + l15) * BSTR + q * 8];
    short8 bu0 = *(const short8*)&sU[(wn * 32 + 0  + l15) * BSTR + q * 8];
    short8 bu1 = *(const short8*)&sU[(wn * 32 + 16 + l15) * BSTR + q * 8];
#pragma unroll
    for (int i = 0; i < 4; i++) {
      short8 af = *(const short8*)&sA[(wm * 64 + i * 16 + l15) * BK + q * 8];
      accG[i][0] = MF(af, bg0, accG[i][0]);
      accG[i][1] = MF(af, bg1, accG[i][1]);
      accU[i][0] = MF(af, bu0, accU[i][0]);
      accU[i][1] = MF(af, bu1, accU[i][1]);
    }
  }
  const size_t obase = (size_t)m0 * NEF + (size_t)e * NF + n0 + wn * 32;
#pragma unroll
  for (int i = 0; i < 4; i++)
#pragma unroll
    for (int j = 0; j < 2; j++)
#pragma unroll
      for (int r = 0; r < 4; r++) {
        int row = wm * 64 + i * 16 + q * 4 + r;
        float g = accG[i][j][r], u = accU[i][j][r];
        float sig = __builtin_amdgcn_rcpf(1.f + __expf(-g));
        gws[obase + (size_t)row * NEF + j * 16 + l15] = bf16_1(u * g * sig * srw[row]);
      }
}

__global__ __launch_bounds__(256, 2) void k_gemm2_legacy(
    const unsigned short* __restrict__ gb, const float* __restrict__ w2,
    float* __restrict__ out)
{
  __shared__ unsigned short sA[BM * BK];
  __shared__ unsigned short sB[BN * BSTR];
  const int mt = blockIdx.x & 15, nt = blockIdx.x >> 4;
  const int m0 = mt * BM, n0 = nt * BN;
  const int tid = threadIdx.x, wid = tid >> 6, lane = tid & 63;
  const int wm = wid >> 1, wn = wid & 1, l15 = lane & 15, q = lane >> 4;
  const int kb0 = blockIdx.y * (NEF / BK / 4), kb1 = kb0 + (NEF / BK / 4);
  floatx4 acc[4][2];
#pragma unroll
  for (int i = 0; i < 4; i++)
#pragma unroll
    for (int j = 0; j < 2; j++) acc[i][j] = (floatx4){0.f, 0.f, 0.f, 0.f};
  const int arow = wid * 32 + (lane >> 2), akoff = (lane & 3) * 8;
  const unsigned short* aptr = gb + (size_t)(m0 + arow) * NEF + akoff;
  unsigned short* aLds = &sA[wid * 32 * BK];
  const float* bptr0 = w2 + (size_t)(wid * 8) * ND + n0 + lane;
  for (int kb = kb0; kb < kb1; ++kb) {
    const float* bp = bptr0 + (size_t)kb * BK * ND;
    float bv[8];
#pragma unroll
    for (int r = 0; r < 8; r++) bv[r] = bp[(size_t)r * ND];
    __syncthreads();
    GLOAD_LDS16(aptr + kb * BK, aLds);
    GLOAD_LDS16(aptr + kb * BK + 16 * NEF, aLds + 16 * BK);
    uint4 wb;
    wb.x = pk_bf16(bv[0], bv[1]); wb.y = pk_bf16(bv[2], bv[3]);
    wb.z = pk_bf16(bv[4], bv[5]); wb.w = pk_bf16(bv[6], bv[7]);
    *((uint4*)&sB[lane * BSTR + wid * 8]) = wb;
    __syncthreads();
    short8 b0 = *(const short8*)&sB[(wn * 32 + 0  + l15) * BSTR + q * 8];
    short8 b1 = *(const short8*)&sB[(wn * 32 + 16 + l15) * BSTR + q * 8];
#pragma unroll
    for (int i = 0; i < 4; i++) {
      short8 af = *(const short8*)&sA[(wm * 64 + i * 16 + l15) * BK + q * 8];
      acc[i][0] = MF(af, b0, acc[i][0]);
      acc[i][1] = MF(af, b1, acc[i][1]);
    }
  }
#pragma unroll
  for (int i = 0; i < 4; i++)
#pragma unroll
    for (int j = 0; j < 2; j++)
#pragma unroll
      for (int r = 0; r < 4; r++) {
        int row = wm * 64 + i * 16 + q * 4 + r;
        unsafeAtomicAdd(&out[(size_t)(m0 + row) * ND + n0 + wn * 32 + j * 16 + l15],
                        acc[i][j][r]);
      }
}

// ---------------------------------------------------------------------------
extern "C" void kernel_launch(void* const* d_in, const int* in_sizes, int n_in,
                              void* d_out, int out_size, void* d_ws, size_t ws_size,
                              hipStream_t stream) {
  const float* x  = (const float*)d_in[0];   // hidden_states (T,D)
  const float* rw = (const float*)d_in[1];   // routing_weights (T,E)
  // d_in[2] router_indices: unused by reference
  const float* w1 = (const float*)d_in[3];   // gate_up_proj (E,D,2F)
  const float* w2 = (const float*)d_in[4];   // down_proj (E,F,D)
  float* out = (float*)d_out;

  // ws layouts:
  //  full: [xb 8MB][gb 100.7MB][w1t 201.3MB][w2t 100.7MB] = 411 MB
  //  slab: [xb 8MB][gb 100.7MB][wtb 50.3MB]               = 159.4 MB
  unsigned short* xb  = (unsigned short*)d_ws;
  unsigned short* gb  = xb + (size_t)NT * ND;
  unsigned short* wtb = gb + (size_t)NT * NEF;
  unsigned short* w1t = wtb;
  unsigned short* w2t = w1t + (size_t)NE * NF2 * ND;
  const size_t WS_FULL = ((size_t)NT * ND + (size_t)NT * NEF +
                          (size_t)NE * NF2 * ND + (size_t)ND * NEF) * 2;  // 411 MB
  const size_t WS_NEED = ((size_t)NT * ND + (size_t)NT * NEF +
                          (size_t)8 * NF2 * ND) * 2;  // 159.4 MB

  hipMemsetAsync(out, 0, (size_t)out_size * sizeof(float), stream);
  k_cvt_x<<<(NT * ND / 4 + 255) / 256, 256, 0, stream>>>(x, xb, NT * ND / 4);

  if (ws_size >= WS_FULL) {
    // -------- full path: 8-phase gemm1 + gemm2, weights transposed up front
    {
      dim3 gt(NF2 / 64, ND / 64, NE);   // 24 x 32 x 32 -- W1 (pair-permuted)
      k_trans<1><<<gt, 256, 0, stream>>>(w1, w1t, ND, NF2, (size_t)ND * NF2);
    }
    {
      dim3 gt(ND / 64, NEF / 64, 1);    // 32 x 384 -- W2
      k_trans<0><<<gt, 256, 0, stream>>>(w2, w2t, NEF, ND, 0);
    }
    k_gemm1p<<<dim3(8 * 6 * NE), 512, 0, stream>>>(xb, w1t, rw, gb);
    k_gemm2p<<<dim3(256), 512, 0, stream>>>(gb, w2t, out);
  } else if (ws_size >= WS_NEED) {
    // -------- slab path (2-phase structure)
    for (int qc = 0; qc < 4; ++qc) {
      dim3 gt(NF2 / 64, ND / 64, 8);
      k_trans<0><<<gt, 256, 0, stream>>>(w1 + (size_t)qc * 8 * ND * NF2, wtb,
                                         ND, NF2, (size_t)ND * NF2);
      dim3 g1(16 * (NF / BN), 8);
      k_gemm1b<<<g1, 256, 0, stream>>>(xb, wtb, rw, gb, qc * 8);
    }
    for (int h = 0; h < 2; ++h) {
      dim3 gt(ND / 64, KH / 64, 1);
      k_trans<0><<<gt, 256, 0, stream>>>(w2 + (size_t)h * KH * ND, wtb, KH, ND, 0);
      dim3 g2(16 * (ND / BN), 2);
      k_gemm2b<KH, KH / BK / 2><<<g2, 256, 0, stream>>>(gb, wtb, out, h * KH);
    }
  } else {
    // legacy fp32-weight path
    dim3 gA(16 * (NF / BN), NE);
    k_gemm1_legacy<<<gA, 256, 0, stream>>>(xb, w1, rw, gb);
    dim3 gB(16 * (ND / BN), 4);
    k_gemm2_legacy<<<gB, 256, 0, stream>>>(gb, w2, out);
  }
}